// Round 7
// baseline (71.928 us; speedup 1.0000x reference)
//
#include <hip/hip_runtime.h>

// Problem constants: N=8, C=1024, D=128, K=64, R=256
#define N_ 8
#define C_ 1024
#define D_ 128
#define K_ 64
#define R_ 256
#define TC 16
#define XPAD 132

typedef float fvec4 __attribute__((ext_vector_type(4)));

// out[n,c,k,d] = (xhat[n,c,d] - cent[n,k,d]) / (8 * ||xhat[n,c]-cent[n,k]||)
// (softmax cancels under the per-k l2norm; final l2norm over K*D == sqrt(K)=8)
//
// R6: two-kernel split. K1 computes xhat (4 MB) + invdist (2 MB) into ws.
// K2 is a fill-shaped pure streamer: linear grid-stride sweep over the output,
// no shuffles/barriers/sqrt in the 268 MB store path. Tests the hypothesis
// that the 57-vs-39 us gap is store-path interleave + non-linear write order.

// ---- K1: per 16-row c-tile, compute xhat rows and 0.125/dist ----
__global__ __launch_bounds__(256) void vlad_prep_kernel(
    const float* __restrict__ x, const float* __restrict__ cluster,
    const int* __restrict__ cluster_idx,
    float* __restrict__ xh_ws, float* __restrict__ id_ws)
{
    __shared__ float xh[TC][XPAD];
    __shared__ float id_s[TC][K_];
    __shared__ float part1[TC][16];
    __shared__ float rinv_s[TC];
    __shared__ int   coff[K_];

    const int bid = blockIdx.x;
    const int n   = bid & 7;
    const int c0  = (bid >> 3) * TC;
    const int t   = threadIdx.x;
    if (t < K_) coff[t] = cluster_idx[t] * D_;

    const int r = t >> 4, s = t & 15;
    const float* xrow = x + (size_t)(n * C_ + c0 + r) * D_ + s * 8;
    fvec4 xa = *(const fvec4*)xrow;
    fvec4 xb = *(const fvec4*)(xrow + 4);
    part1[r][s] = xa.x*xa.x + xa.y*xa.y + xa.z*xa.z + xa.w*xa.w
                + xb.x*xb.x + xb.y*xb.y + xb.z*xb.z + xb.w*xb.w;
    __syncthreads();
    if (t < TC) {
        const fvec4* pp = (const fvec4*)part1[t];
        fvec4 v = pp[0] + pp[1] + pp[2] + pp[3];
        rinv_s[t] = 1.0f / fmaxf(sqrtf(v.x + v.y + v.z + v.w), 1e-12f);
    }
    __syncthreads();
    const float rv = rinv_s[r];
    xa *= rv; xb *= rv;
    *(fvec4*)&xh[r][s * 8]     = xa;
    *(fvec4*)&xh[r][s * 8 + 4] = xb;
    float* xd = xh_ws + (size_t)(n * C_ + c0 + r) * D_ + s * 8;
    *(fvec4*)xd       = xa;
    *(fvec4*)(xd + 4) = xb;
    __syncthreads();

    {   // distances, thread-local dots (same as R5)
        const int c  = t & 15;
        const int g  = (t >> 4) & 3;
        const int kb = t >> 6;
        const float* cb = cluster + (size_t)n * (R_ * D_) + g * 32;
        fvec4 xr[8];
        #pragma unroll
        for (int j = 0; j < 8; ++j) xr[j] = *(const fvec4*)&xh[c][g * 32 + j * 4];
        for (int ki = 0; ki < 16; ++ki) {
            const int k = kb * 16 + ki;
            const float* crow = cb + coff[k];
            float acc = 0.f;
            #pragma unroll
            for (int j = 0; j < 8; ++j) {
                fvec4 cv = *(const fvec4*)(crow + j * 4);
                fvec4 d  = xr[j] - cv;
                acc = fmaf(d.x, d.x, fmaf(d.y, d.y, fmaf(d.z, d.z, fmaf(d.w, d.w, acc))));
            }
            acc += __shfl_xor(acc, 16);
            acc += __shfl_xor(acc, 32);
            if (g == 0) id_s[c][k] = 0.125f / fmaxf(sqrtf(acc), 1e-12f);
        }
    }
    __syncthreads();
    // id_s is [16][64] = 1024 contiguous floats = 256 fvec4; thread t writes one
    ((fvec4*)(id_ws + (size_t)(n * C_ + c0) * K_))[t] = ((const fvec4*)id_s)[t];
}

// ---- K2: fill-shaped streamer. j = global float4 index, linear sweep. ----
// k = (tid>>5)&63 is constant per thread; n = i>>2 is compile-time per iter.
__global__ __launch_bounds__(256) void vlad_store_kernel(
    const float* __restrict__ cluster, const int* __restrict__ cluster_idx,
    const float* __restrict__ xh_ws, const float* __restrict__ id_ws,
    float* __restrict__ out)
{
    const int tid = blockIdx.x * 256 + threadIdx.x;   // 0 .. 2^19-1
    const int d4  = tid & 31;
    const int k   = (tid >> 5) & 63;
    const int ck  = cluster_idx[k] * D_ + d4 * 4;

    #pragma unroll
    for (int n = 0; n < N_; ++n) {
        const fvec4 cv = *(const fvec4*)(cluster + (size_t)n * (R_ * D_) + ck);
        #pragma unroll
        for (int b = 0; b < 4; ++b) {
            const int j  = tid + ((n * 4 + b) << 19);  // n == j>>21 by construction
            const int nc = j >> 11;                    // n*C + c
            const fvec4 xv  = *(const fvec4*)(xh_ws + ((size_t)nc << 7) + (d4 << 2));
            const float idv = id_ws[j >> 5];
            *(fvec4*)((float*)out + ((size_t)j << 2)) = (xv - cv) * idv;
        }
    }
}

// ---- fallback (R1-style single kernel) if ws is unexpectedly small ----
__global__ __launch_bounds__(256) void vlad_fallback_kernel(
    const float* __restrict__ x, const float* __restrict__ cluster,
    const int* __restrict__ cluster_idx, float* __restrict__ out)
{
    const int blk = blockIdx.x, n = blk >> 10, t = threadIdx.x;
    const int l = t & 31, h = t >> 5;
    fvec4 xv = *(const fvec4*)(x + (size_t)blk * D_ + l * 4);
    const float* cbase = cluster + (size_t)n * (R_ * D_);
    fvec4 cv[8];
    #pragma unroll
    for (int p = 0; p < 8; ++p)
        cv[p] = *(const fvec4*)(cbase + (size_t)cluster_idx[p * 8 + h] * D_ + l * 4);
    float nx = fmaf(xv.x, xv.x, fmaf(xv.y, xv.y, fmaf(xv.z, xv.z, xv.w * xv.w)));
    #pragma unroll
    for (int m = 1; m <= 16; m <<= 1) nx += __shfl_xor(nx, m, 32);
    xv *= (1.0f / fmaxf(sqrtf(nx), 1e-12f));
    float* orow = out + (size_t)blk * (K_ * D_) + (size_t)t * 4;
    #pragma unroll
    for (int p = 0; p < 8; ++p) {
        fvec4 d = xv - cv[p];
        float ds = fmaf(d.x, d.x, fmaf(d.y, d.y, fmaf(d.z, d.z, d.w * d.w)));
        #pragma unroll
        for (int m = 1; m <= 16; m <<= 1) ds += __shfl_xor(ds, m, 32);
        *(fvec4*)(orow + (size_t)p * 1024) = d * (0.125f / fmaxf(sqrtf(ds), 1e-12f));
    }
}

extern "C" void kernel_launch(void* const* d_in, const int* in_sizes, int n_in,
                              void* d_out, int out_size, void* d_ws, size_t ws_size,
                              hipStream_t stream) {
    const float* x           = (const float*)d_in[0];
    const float* cluster     = (const float*)d_in[1];
    const int*   cluster_idx = (const int*)d_in[4];
    float* out = (float*)d_out;

    const size_t need = (size_t)(N_ * C_ * D_ + N_ * C_ * K_) * sizeof(float); // 6 MB
    if (ws_size < need) {
        vlad_fallback_kernel<<<dim3(N_ * C_), dim3(256), 0, stream>>>(x, cluster, cluster_idx, out);
        return;
    }
    float* xh_ws = (float*)d_ws;
    float* id_ws = xh_ws + (size_t)N_ * C_ * D_;

    vlad_prep_kernel<<<dim3(N_ * C_ / TC), dim3(256), 0, stream>>>(
        x, cluster, cluster_idx, xh_ws, id_ws);
    vlad_store_kernel<<<dim3((N_ * C_ * K_ * D_ / 4) / (4 * N_) / 256), dim3(256), 0, stream>>>(
        cluster, cluster_idx, xh_ws, id_ws, out);
}